// Round 3
// baseline (994.818 us; speedup 1.0000x reference)
//
#include <hip/hip_runtime.h>
#include <hip/hip_bf16.h>
#include <math.h>

#define H 512
#define NT 6

// edge GEMM tile
#define EBM 128
#define EBN 128
#define EBK 32
// gru GEMM tile
#define GBM 128
#define GBN 64
#define GBK 32

typedef short bf16x8 __attribute__((ext_vector_type(8)));
typedef float f32x4 __attribute__((ext_vector_type(4)));

__device__ __forceinline__ float sigmoidf_(float x) { return 1.0f / (1.0f + expf(-x)); }

__device__ __forceinline__ unsigned short f2bf(float f) {
    unsigned int u = __float_as_uint(f);
    u = (u + 0x7FFF + ((u >> 16) & 1)) >> 16;
    return (unsigned short)u;
}

// async global->LDS, 16B per lane. LDS dest must be lane-linear (wave base + lane*16);
// global src may be per-lane (gather ok).
__device__ __forceinline__ void glds16(const void* g, void* l) {
    __builtin_amdgcn_global_load_lds((const __attribute__((address_space(1))) unsigned int*)g,
                                     (__attribute__((address_space(3))) unsigned int*)l,
                                     16, 0, 0);
}

// counted-vmcnt wait + raw barrier (T4): tile-t loads landed, t+1/t+2 stay in flight.
// wait BEFORE barrier (each wave's own DMA must land; barrier publishes cross-wave).
#define WAITBAR(N)                                         \
    {                                                      \
        asm volatile("s_waitcnt vmcnt(" #N ")" ::: "memory"); \
        __builtin_amdgcn_s_barrier();                      \
        asm volatile("" ::: "memory");                     \
    }

// ---------------- edge-type counting sort (block-aggregated atomics) ----------------
// meta layout (ints): [0..7]=counts, [8..14]=paddedStart (NT+1 used), [16..23]=cursor
__global__ void hist_kernel(const int* __restrict__ etype, int E, int* __restrict__ meta) {
    __shared__ int lh[NT];
    if (threadIdx.x < NT) lh[threadIdx.x] = 0;
    __syncthreads();
    int i = blockIdx.x * blockDim.x + threadIdx.x;
    if (i < E) atomicAdd(&lh[etype[i]], 1);
    __syncthreads();
    if (threadIdx.x < NT) {
        int c = lh[threadIdx.x];
        if (c) atomicAdd(&meta[threadIdx.x], c);
    }
}

__global__ void prefix_kernel(int* __restrict__ meta) {
    if (threadIdx.x == 0 && blockIdx.x == 0) {
        int acc = 0;
        for (int t = 0; t < NT; ++t) {
            meta[8 + t]  = acc;
            meta[16 + t] = acc;
            acc += ((meta[t] + EBM - 1) / EBM) * EBM;
        }
        meta[8 + NT] = acc;
    }
}

__global__ void scatter_perm_kernel(const int* __restrict__ etype, int E,
                                    int* __restrict__ meta, int* __restrict__ perm) {
    __shared__ int lcount[NT];
    __shared__ int lbase[NT];
    const int tid = threadIdx.x;
    if (tid < NT) lcount[tid] = 0;
    __syncthreads();
    int i = blockIdx.x * blockDim.x + tid;
    int t = 0, rank = 0;
    if (i < E) {
        t = etype[i];
        rank = atomicAdd(&lcount[t], 1);      // intra-block rank (LDS)
    }
    __syncthreads();
    if (tid < NT) {
        int c = lcount[tid];
        lbase[tid] = c ? atomicAdd(&meta[16 + tid], c) : 0;  // reserve block span
    }
    __syncthreads();
    if (i < E) perm[lbase[t] + rank] = i;
}

// ---------------- fp32 -> bf16 elementwise (x4) ----------------
__global__ void conv_bf16_kernel(const float* __restrict__ in, unsigned short* __restrict__ out, int n4) {
    int i = blockIdx.x * blockDim.x + threadIdx.x;
    if (i < n4) {
        float4 v = ((const float4*)in)[i];
        ushort4 o;
        o.x = f2bf(v.x); o.y = f2bf(v.y); o.z = f2bf(v.z); o.w = f2bf(v.w);
        ((ushort4*)out)[i] = o;
    }
}

// ---------------- GRU weights -> bf16, transposed B^T[n][k] ----------------
__global__ void conv_gru_w_kernel(const float* __restrict__ Wir, const float* __restrict__ Wiz,
                                  const float* __restrict__ Win, const float* __restrict__ Whr,
                                  const float* __restrict__ Whz, const float* __restrict__ Whn,
                                  unsigned short* __restrict__ Brt, unsigned short* __restrict__ Bzt,
                                  unsigned short* __restrict__ Bnit, unsigned short* __restrict__ Bnht) {
    int idx = blockIdx.x * blockDim.x + threadIdx.x;
    if (idx >= 512 * 1024) return;
    int n = idx >> 10;
    int k = idx & 1023;
    int kk = k & 511;
    const float* wr = (k < 512) ? Wir : Whr;
    const float* wz = (k < 512) ? Wiz : Whz;
    Brt[idx] = f2bf(wr[kk * H + n]);
    Bzt[idx] = f2bf(wz[kk * H + n]);
    if (k < 512) Bnit[n * H + k]  = f2bf(Win[k * H + n]);
    else         Bnht[n * H + kk] = f2bf(Whn[kk * H + n]);
}

// W_edge (512 x 3072) -> WeT[3072][512] bf16
__global__ void conv_edge_w_kernel(const float* __restrict__ W_edge, unsigned short* __restrict__ WeT) {
    int idx = blockIdx.x * blockDim.x + threadIdx.x;
    if (idx >= 3072 * 512) return;
    int n = idx >> 9;
    int k = idx & 511;
    WeT[idx] = f2bf(W_edge[(size_t)k * (NT * H) + n]);
}

// ---------------- edge message GEMM (MFMA, 128x128, depth-2 counted-vmcnt) + scatter-add ----------------
__global__ __launch_bounds__(256)
void edge_msg_mfma(const unsigned short* __restrict__ emb_bf,
                   const int* __restrict__ src_idx,
                   const int* __restrict__ dst_idx,
                   const float* __restrict__ b_edge,
                   const unsigned short* __restrict__ WeT,
                   const int* __restrict__ meta,
                   const int* __restrict__ perm,
                   float* __restrict__ proposed)
{
    __shared__ short As[4][EBM * EBK];   // 4 x 8KB, linear (required by global_load_lds)
    __shared__ short Bs[4][EBN * EBK];   // 4 x 8KB -> 64KB total
    __shared__ int ls_src[EBM];
    __shared__ int ls_dst[EBM];

    const int rowBase = blockIdx.y * EBM;
    if (rowBase >= meta[8 + NT]) return;
    int t = 0;
    while (rowBase >= meta[8 + t + 1]) ++t;

    const int colBase = blockIdx.x * EBN;
    const int tid = threadIdx.x;

    if (tid < EBM) {
        int e = perm[rowBase + tid];
        int s = 0, d = -1;                       // padded rows read row 0 (results discarded)
        if (e >= 0) { s = src_idx[e] * H; d = dst_idx[e] * H; }
        ls_src[tid] = s;
        ls_dst[tid] = d;
    }
    __syncthreads();

    const int lane = tid & 63;
    const int wave = tid >> 6;
    const int wm = (wave >> 1) * 64;             // wave tile 64x64 of the 128x128 block
    const int wn = (wave & 1) * 64;
    const int q = lane >> 4;
    const int r = lane & 15;

    const int rA   = tid >> 2;                   // 0..63: staging row within half-tile
    const int slot = (tid & 3) * 8;              // 0/8/16/24 shorts (16B chunk)

    const int s0 = ls_src[rA];
    const int s1 = ls_src[64 + rA];
    const size_t b0 = ((size_t)(t * H + colBase + rA)) * H + slot;
    const size_t b1 = ((size_t)(t * H + colBase + 64 + rA)) * H + slot;

    f32x4 acc[4][4];
    #pragma unroll
    for (int i = 0; i < 4; ++i)
        #pragma unroll
        for (int j = 0; j < 4; ++j) acc[i][j] = (f32x4){0.f, 0.f, 0.f, 0.f};

// issue K-tile S's DMA into buffer B (4 loads/thread)
#define ESTAGE(S, B)                                                        \
    {                                                                       \
        const int k0_ = (S) * EBK;                                          \
        glds16(emb_bf + (size_t)s0 + k0_ + slot, &As[B][tid * 8]);          \
        glds16(emb_bf + (size_t)s1 + k0_ + slot, &As[B][(256 + tid) * 8]);  \
        glds16(WeT + b0 + k0_, &Bs[B][tid * 8]);                            \
        glds16(WeT + b1 + k0_, &Bs[B][(256 + tid) * 8]);                    \
    }

#define ECOMPUTE(B)                                                                          \
    {                                                                                        \
        bf16x8 a[4];                                                                         \
        _Pragma("unroll")                                                                    \
        for (int i = 0; i < 4; ++i)                                                          \
            a[i] = *(const bf16x8*)&As[B][(wm + i * 16 + r) * EBK + q * 8];                  \
        _Pragma("unroll")                                                                    \
        for (int j = 0; j < 4; ++j) {                                                        \
            bf16x8 b = *(const bf16x8*)&Bs[B][(wn + j * 16 + r) * EBK + q * 8];              \
            _Pragma("unroll")                                                                \
            for (int i = 0; i < 4; ++i)                                                      \
                acc[i][j] = __builtin_amdgcn_mfma_f32_16x16x32_bf16(a[i], b, acc[i][j], 0, 0, 0); \
        }                                                                                    \
    }

    ESTAGE(0, 0);
    ESTAGE(1, 1);
    // 16 K-steps; steady state keeps 2 stages (8 loads) in flight across the barrier
    for (int s = 0; s < 14; ++s) {
        ESTAGE(s + 2, (s + 2) & 3);
        WAITBAR(8);
        ECOMPUTE(s & 3);
    }
    WAITBAR(4);
    ECOMPUTE(2);            // s = 14
    WAITBAR(0);
    ECOMPUTE(3);            // s = 15
#undef ESTAGE
#undef ECOMPUTE

    int cols[4];
    float bias[4];
    #pragma unroll
    for (int j = 0; j < 4; ++j) {
        cols[j] = colBase + wn + j * 16 + r;
        bias[j] = b_edge[t * H + cols[j]];
    }
    #pragma unroll
    for (int i = 0; i < 4; ++i) {
        #pragma unroll
        for (int reg = 0; reg < 4; ++reg) {
            int row = wm + i * 16 + q * 4 + reg;
            int d = ls_dst[row];
            if (d < 0) continue;
            #pragma unroll
            for (int j = 0; j < 4; ++j)
                atomicAdd(&proposed[(size_t)d + cols[j]], acc[i][j][reg] + bias[j]);
        }
    }
}

// ---------------- fused GRU (MFMA, 128x64, depth-2 counted-vmcnt): A' = [P | H] over K=1024 ----------------
__global__ __launch_bounds__(256)
void gru_mfma(const unsigned short* __restrict__ prop_bf,
              const unsigned short* __restrict__ emb_bf,
              const float* __restrict__ emb_f32,
              const unsigned short* __restrict__ Brt,
              const unsigned short* __restrict__ Bzt,
              const unsigned short* __restrict__ Bnit,
              const unsigned short* __restrict__ Bnht,
              const float* __restrict__ bir, const float* __restrict__ biz,
              const float* __restrict__ bin, const float* __restrict__ bhn,
              float* __restrict__ out, int N)
{
    __shared__ short As[4][GBM * GBK];    // 4 x 8KB linear
    __shared__ short Brs[4][GBN * GBK];   // 4 x 4KB
    __shared__ short Bzs[4][GBN * GBK];
    __shared__ short Bns[4][GBN * GBK];   // total 80KB -> 2 blocks/CU

    // XCD-aware swizzle (T1): contiguous logical-tile chunk per XCD.
    int wg = blockIdx.y * gridDim.x + blockIdx.x;
    const int nwg = gridDim.x * gridDim.y;
    if ((nwg & 7) == 0) {
        const int cpx = nwg >> 3;
        wg = (wg & 7) * cpx + (wg >> 3);
    }
    const int rowBase = (wg / gridDim.x) * GBM;
    const int colBase = (wg % gridDim.x) * GBN;

    const int tid = threadIdx.x;
    const int lane = tid & 63;
    const int wave = tid >> 6;
    const int wm = (wave >> 1) * 64;             // wave tile 64 rows x 32 cols
    const int wn = (wave & 1) * 32;
    const int q = lane >> 4;
    const int r = lane & 15;

    const int rA   = tid >> 2;                   // 0..63
    const int slot = (tid & 3) * 8;

    const size_t aOff0  = (size_t)(rowBase + rA) * H + slot;
    const size_t aOff1  = (size_t)(rowBase + 64 + rA) * H + slot;
    const size_t bOffRZ = (size_t)(colBase + rA) * 1024 + slot;
    const size_t bOffN  = (size_t)(colBase + rA) * 512 + slot;

    f32x4 accR[4][2], accZ[4][2], accNI[4][2], accNH[4][2];
    #pragma unroll
    for (int i = 0; i < 4; ++i)
        #pragma unroll
        for (int j = 0; j < 2; ++j) {
            accR[i][j] = (f32x4){0.f, 0.f, 0.f, 0.f};
            accZ[i][j] = accR[i][j];
            accNI[i][j] = accR[i][j];
            accNH[i][j] = accR[i][j];
        }

// stage K-step S (0..31) into buffer B (5 loads/thread). Source select is wave-uniform.
#define GSTAGE(S, B)                                                     \
    {                                                                    \
        const unsigned short* Asrc_ = ((S) < 16) ? prop_bf : emb_bf;     \
        const unsigned short* Bn_   = ((S) < 16) ? Bnit : Bnht;          \
        const int kk_ = ((S) & 15) * GBK;                                \
        const int k0_ = (S) * GBK;                                       \
        glds16(Asrc_ + aOff0 + kk_, &As[B][tid * 8]);                    \
        glds16(Asrc_ + aOff1 + kk_, &As[B][(256 + tid) * 8]);            \
        glds16(Brt + bOffRZ + k0_, &Brs[B][tid * 8]);                    \
        glds16(Bzt + bOffRZ + k0_, &Bzs[B][tid * 8]);                    \
        glds16(Bn_ + bOffN + kk_, &Bns[B][tid * 8]);                     \
    }

// compute one K-step from buffer B; n-gate accumulator chosen at compile time
#define GCOMPUTE(ACCN, B)                                                                            \
    {                                                                                                \
        bf16x8 a[4];                                                                                 \
        _Pragma("unroll")                                                                            \
        for (int i = 0; i < 4; ++i)                                                                  \
            a[i] = *(const bf16x8*)&As[B][(wm + i * 16 + r) * GBK + q * 8];                          \
        _Pragma("unroll")                                                                            \
        for (int j = 0; j < 2; ++j) {                                                                \
            bf16x8 br = *(const bf16x8*)&Brs[B][(wn + j * 16 + r) * GBK + q * 8];                    \
            bf16x8 bz = *(const bf16x8*)&Bzs[B][(wn + j * 16 + r) * GBK + q * 8];                    \
            bf16x8 bn = *(const bf16x8*)&Bns[B][(wn + j * 16 + r) * GBK + q * 8];                    \
            _Pragma("unroll")                                                                        \
            for (int i = 0; i < 4; ++i) {                                                            \
                accR[i][j] = __builtin_amdgcn_mfma_f32_16x16x32_bf16(a[i], br, accR[i][j], 0, 0, 0); \
                accZ[i][j] = __builtin_amdgcn_mfma_f32_16x16x32_bf16(a[i], bz, accZ[i][j], 0, 0, 0); \
                ACCN[i][j] = __builtin_amdgcn_mfma_f32_16x16x32_bf16(a[i], bn, ACCN[i][j], 0, 0, 0); \
            }                                                                                        \
        }                                                                                            \
    }

    GSTAGE(0, 0);
    GSTAGE(1, 1);
    // 32 K-steps; steady state keeps 2 stages (10 loads) in flight across the barrier
    for (int s = 0; s < 16; ++s) {               // P-half: n-gate -> accNI
        GSTAGE(s + 2, (s + 2) & 3);
        WAITBAR(10);
        GCOMPUTE(accNI, s & 3);
    }
    for (int s = 16; s < 30; ++s) {              // H-half: n-gate -> accNH
        GSTAGE(s + 2, (s + 2) & 3);
        WAITBAR(10);
        GCOMPUTE(accNH, s & 3);
    }
    WAITBAR(5);
    GCOMPUTE(accNH, 2);     // s = 30
    WAITBAR(0);
    GCOMPUTE(accNH, 3);     // s = 31
#undef GSTAGE
#undef GCOMPUTE

    #pragma unroll
    for (int j = 0; j < 2; ++j) {
        const int col = colBase + wn + j * 16 + r;
        const float vbir = bir[col], vbiz = biz[col], vbin = bin[col], vbhn = bhn[col];
        #pragma unroll
        for (int i = 0; i < 4; ++i) {
            #pragma unroll
            for (int reg = 0; reg < 4; ++reg) {
                const int row = rowBase + wm + i * 16 + q * 4 + reg;
                if (row >= N) continue;
                float rg = sigmoidf_(accR[i][j][reg] + vbir);
                float zg = sigmoidf_(accZ[i][j][reg] + vbiz);
                float ng = tanhf(accNI[i][j][reg] + vbin + rg * (accNH[i][j][reg] + vbhn));
                float h = emb_f32[(size_t)row * H + col];
                out[(size_t)row * H + col] = (1.0f - zg) * ng + zg * h;
            }
        }
    }
}

extern "C" void kernel_launch(void* const* d_in, const int* in_sizes, int n_in,
                              void* d_out, int out_size, void* d_ws, size_t ws_size,
                              hipStream_t stream) {
    const float* emb     = (const float*)d_in[0];
    const int*   src_idx = (const int*)d_in[1];
    const int*   dst_idx = (const int*)d_in[2];
    const int*   etype   = (const int*)d_in[3];
    const float* W_edge  = (const float*)d_in[6];
    const float* b_edge  = (const float*)d_in[7];
    const float* Wir = (const float*)d_in[8];
    const float* Wiz = (const float*)d_in[9];
    const float* Win = (const float*)d_in[10];
    const float* bir = (const float*)d_in[11];
    const float* biz = (const float*)d_in[12];
    const float* bin = (const float*)d_in[13];
    const float* Whr = (const float*)d_in[14];
    const float* Whz = (const float*)d_in[15];
    const float* Whn = (const float*)d_in[16];
    const float* bhn = (const float*)d_in[17];

    const int E = in_sizes[1];
    const int N = in_sizes[0] / H;
    const int NH = N * H;

    char* ws = (char*)d_ws;
    float*          proposed = (float*)ws;                       ws += (size_t)NH * 4;
    unsigned short* prop_bf  = (unsigned short*)ws;              ws += (size_t)NH * 2;
    unsigned short* emb_bf   = (unsigned short*)ws;              ws += (size_t)NH * 2;
    unsigned short* Brt      = (unsigned short*)ws;              ws += 512 * 1024 * 2;
    unsigned short* Bzt      = (unsigned short*)ws;              ws += 512 * 1024 * 2;
    unsigned short* Bnit     = (unsigned short*)ws;              ws += 512 * 512 * 2;
    unsigned short* Bnht     = (unsigned short*)ws;              ws += 512 * 512 * 2;
    unsigned short* WeT      = (unsigned short*)ws;              ws += 3072 * 512 * 2;
    int*            meta     = (int*)ws;                         ws += 32 * 4;
    int*            perm     = (int*)ws;
    const int maxRowTiles = (E + EBM - 1) / EBM + NT;

    hipMemsetAsync(proposed, 0, (size_t)NH * 4, stream);
    hipMemsetAsync(meta, 0, 32 * 4, stream);
    hipMemsetAsync(perm, 0xFF, (size_t)maxRowTiles * EBM * 4, stream);

    const int n4 = NH / 4;
    conv_bf16_kernel<<<(n4 + 255) / 256, 256, 0, stream>>>(emb, emb_bf, n4);
    conv_gru_w_kernel<<<(512 * 1024 + 255) / 256, 256, 0, stream>>>(
        Wir, Wiz, Win, Whr, Whz, Whn, Brt, Bzt, Bnit, Bnht);
    conv_edge_w_kernel<<<(3072 * 512 + 255) / 256, 256, 0, stream>>>(W_edge, WeT);

    hist_kernel<<<(E + 255) / 256, 256, 0, stream>>>(etype, E, meta);
    prefix_kernel<<<1, 64, 0, stream>>>(meta);
    scatter_perm_kernel<<<(E + 255) / 256, 256, 0, stream>>>(etype, E, meta, perm);

    dim3 egrid(H / EBN, maxRowTiles);
    edge_msg_mfma<<<egrid, 256, 0, stream>>>(emb_bf, src_idx, dst_idx, b_edge, WeT,
                                             meta, perm, proposed);

    conv_bf16_kernel<<<(n4 + 255) / 256, 256, 0, stream>>>(proposed, prop_bf, n4);

    dim3 ggrid(H / GBN, (N + GBM - 1) / GBM);
    gru_mfma<<<ggrid, 256, 0, stream>>>(prop_bf, emb_bf, emb, Brt, Bzt, Bnit, Bnht,
                                        bir, biz, bin, bhn, (float*)d_out, N);
}

// Round 5
// 781.627 us; speedup vs baseline: 1.2728x; 1.2728x over previous
//
#include <hip/hip_runtime.h>
#include <hip/hip_bf16.h>
#include <math.h>

#define H 512
#define NT 6

// edge GEMM tile
#define EBM 128
#define EBN 128
#define EBK 32
// gru GEMM tile
#define GBM 128
#define GBN 64
#define GBK 32

// fixed-point scale for deterministic edge scatter (int32 atomics)
#define PSCALE 65536.0f
#define PINV   (1.0f / 65536.0f)

typedef short bf16x8 __attribute__((ext_vector_type(8)));
typedef float f32x4 __attribute__((ext_vector_type(4)));

__device__ __forceinline__ float sigmoidf_(float x) { return 1.0f / (1.0f + expf(-x)); }

__device__ __forceinline__ unsigned short f2bf(float f) {
    unsigned int u = __float_as_uint(f);
    u = (u + 0x7FFF + ((u >> 16) & 1)) >> 16;
    return (unsigned short)u;
}

// async global->LDS, 16B per lane. LDS dest must be lane-linear (wave base + lane*16);
// global src may be per-lane (gather ok).
__device__ __forceinline__ void glds16(const void* g, void* l) {
    __builtin_amdgcn_global_load_lds((const __attribute__((address_space(1))) unsigned int*)g,
                                     (__attribute__((address_space(3))) unsigned int*)l,
                                     16, 0, 0);
}

// counted-vmcnt wait + raw barrier (T4).
// CRITICAL (r4 race fix): drain lgkmcnt(0) BEFORE the barrier — raw s_barrier has no
// implicit waitcnt, so without this a wave can pass the barrier with its own ds_reads
// of buf[(S-1)%3] still pending while another wave's stage(S+2) DMA overwrites it.
// vmcnt stays counted (N) so prefetch loads span the barrier (the T4 win).
#define WAITBAR(N)                                                        \
    {                                                                     \
        asm volatile("s_waitcnt vmcnt(" #N ") lgkmcnt(0)" ::: "memory");  \
        __builtin_amdgcn_s_barrier();                                     \
        asm volatile("" ::: "memory");                                    \
    }

// ---------------- edge-type counting sort (block-aggregated atomics) ----------------
// meta layout (ints): [0..7]=counts, [8..14]=paddedStart (NT+1 used), [16..23]=cursor
__global__ void hist_kernel(const int* __restrict__ etype, int E, int* __restrict__ meta) {
    __shared__ int lh[NT];
    if (threadIdx.x < NT) lh[threadIdx.x] = 0;
    __syncthreads();
    int i = blockIdx.x * blockDim.x + threadIdx.x;
    if (i < E) atomicAdd(&lh[etype[i]], 1);
    __syncthreads();
    if (threadIdx.x < NT) {
        int c = lh[threadIdx.x];
        if (c) atomicAdd(&meta[threadIdx.x], c);
    }
}

__global__ void prefix_kernel(int* __restrict__ meta) {
    if (threadIdx.x == 0 && blockIdx.x == 0) {
        int acc = 0;
        for (int t = 0; t < NT; ++t) {
            meta[8 + t]  = acc;
            meta[16 + t] = acc;
            acc += ((meta[t] + EBM - 1) / EBM) * EBM;
        }
        meta[8 + NT] = acc;
    }
}

__global__ void scatter_perm_kernel(const int* __restrict__ etype, int E,
                                    int* __restrict__ meta, int* __restrict__ perm) {
    __shared__ int lcount[NT];
    __shared__ int lbase[NT];
    const int tid = threadIdx.x;
    if (tid < NT) lcount[tid] = 0;
    __syncthreads();
    int i = blockIdx.x * blockDim.x + tid;
    int t = 0, rank = 0;
    if (i < E) {
        t = etype[i];
        rank = atomicAdd(&lcount[t], 1);      // intra-block rank (LDS)
    }
    __syncthreads();
    if (tid < NT) {
        int c = lcount[tid];
        lbase[tid] = c ? atomicAdd(&meta[16 + tid], c) : 0;  // reserve block span
    }
    __syncthreads();
    if (i < E) perm[lbase[t] + rank] = i;
}

// ---------------- fp32 -> bf16 into AH[N][1024] high half (emb) ----------------
__global__ void conv_to_ah(const float* __restrict__ in, unsigned short* __restrict__ AH,
                           int n4, int half) {
    int i = blockIdx.x * blockDim.x + threadIdx.x;
    if (i < n4) {
        float4 v = ((const float4*)in)[i];
        ushort4 o;
        o.x = f2bf(v.x); o.y = f2bf(v.y); o.z = f2bf(v.z); o.w = f2bf(v.w);
        int row = i >> 7;            // 128 float4 per 512-col row
        int c4  = i & 127;
        ((ushort4*)AH)[row * 256 + half * 128 + c4] = o;   // AH row stride 1024 shorts
    }
}

// ---------------- int32 fixed-point -> bf16 into AH[N][1024] low half (proposed) ----------------
__global__ void conv_i2ah(const int* __restrict__ in, unsigned short* __restrict__ AH, int n4) {
    int i = blockIdx.x * blockDim.x + threadIdx.x;
    if (i < n4) {
        int4 v = ((const int4*)in)[i];
        ushort4 o;
        o.x = f2bf((float)v.x * PINV); o.y = f2bf((float)v.y * PINV);
        o.z = f2bf((float)v.z * PINV); o.w = f2bf((float)v.w * PINV);
        int row = i >> 7;
        int c4  = i & 127;
        ((ushort4*)AH)[row * 256 + c4] = o;                // low half
    }
}

// ---------------- GRU weights -> bf16, transposed B^T[n][k], K=1024 = [input | hidden] ----------------
__global__ void conv_gru_w_kernel(const float* __restrict__ Wir, const float* __restrict__ Wiz,
                                  const float* __restrict__ Win, const float* __restrict__ Whr,
                                  const float* __restrict__ Whz, const float* __restrict__ Whn,
                                  unsigned short* __restrict__ Brt, unsigned short* __restrict__ Bzt,
                                  unsigned short* __restrict__ Bnt) {
    int idx = blockIdx.x * blockDim.x + threadIdx.x;
    if (idx >= 512 * 1024) return;
    int n = idx >> 10;
    int k = idx & 1023;
    int kk = k & 511;
    const float* wr = (k < 512) ? Wir : Whr;
    const float* wz = (k < 512) ? Wiz : Whz;
    const float* wn = (k < 512) ? Win : Whn;
    Brt[idx] = f2bf(wr[kk * H + n]);
    Bzt[idx] = f2bf(wz[kk * H + n]);
    Bnt[idx] = f2bf(wn[kk * H + n]);
}

// W_edge (512 x 3072) -> WeT[3072][512] bf16
__global__ void conv_edge_w_kernel(const float* __restrict__ W_edge, unsigned short* __restrict__ WeT) {
    int idx = blockIdx.x * blockDim.x + threadIdx.x;
    if (idx >= 3072 * 512) return;
    int n = idx >> 9;
    int k = idx & 511;
    WeT[idx] = f2bf(W_edge[(size_t)k * (NT * H) + n]);
}

// ---------------- edge message GEMM (MFMA, 128x128, 3-buf counted-vmcnt) + int scatter-add ----------------
__global__ __launch_bounds__(256)
void edge_msg_mfma(const unsigned short* __restrict__ AH,
                   const int* __restrict__ src_idx,
                   const int* __restrict__ dst_idx,
                   const float* __restrict__ b_edge,
                   const unsigned short* __restrict__ WeT,
                   const int* __restrict__ meta,
                   const int* __restrict__ perm,
                   int* __restrict__ proposed)
{
    __shared__ short As[3][EBM * EBK];   // 3 x 8KB, linear (required by global_load_lds)
    __shared__ short Bs[3][EBN * EBK];   // 3 x 8KB -> 48KB total
    __shared__ int ls_src[EBM];
    __shared__ int ls_dst[EBM];

    const int rowBase = blockIdx.y * EBM;
    if (rowBase >= meta[8 + NT]) return;
    int t = 0;
    while (rowBase >= meta[8 + t + 1]) ++t;

    const int colBase = blockIdx.x * EBN;
    const int tid = threadIdx.x;

    if (tid < EBM) {
        int e = perm[rowBase + tid];
        int s = 512, d = -1;                     // padded rows read row 0's emb half (discarded)
        if (e >= 0) { s = src_idx[e] * 1024 + 512; d = dst_idx[e] * H; }  // emb lives in AH high half
        ls_src[tid] = s;
        ls_dst[tid] = d;
    }
    __syncthreads();

    const int lane = tid & 63;
    const int wave = tid >> 6;
    const int wm = (wave >> 1) * 64;             // wave tile 64x64 of the 128x128 block
    const int wn = (wave & 1) * 64;
    const int q = lane >> 4;
    const int r = lane & 15;

    const int rA   = tid >> 2;                   // 0..63: staging row within half-tile
    const int slot = (tid & 3) * 8;              // 0/8/16/24 shorts (16B chunk)

    const int s0 = ls_src[rA];
    const int s1 = ls_src[64 + rA];
    const size_t b0 = ((size_t)(t * H + colBase + rA)) * H + slot;
    const size_t b1 = ((size_t)(t * H + colBase + 64 + rA)) * H + slot;

    f32x4 acc[4][4];
    #pragma unroll
    for (int i = 0; i < 4; ++i)
        #pragma unroll
        for (int j = 0; j < 4; ++j) acc[i][j] = (f32x4){0.f, 0.f, 0.f, 0.f};

// issue K-tile S's DMA into buffer B (4 loads/thread)
#define ESTAGE(S, B)                                                         \
    {                                                                        \
        glds16(AH + (size_t)s0 + (S) * EBK + slot, &As[B][tid * 8]);         \
        glds16(AH + (size_t)s1 + (S) * EBK + slot, &As[B][(256 + tid) * 8]); \
        glds16(WeT + b0 + (S) * EBK, &Bs[B][tid * 8]);                       \
        glds16(WeT + b1 + (S) * EBK, &Bs[B][(256 + tid) * 8]);               \
    }

#define ECOMPUTE(B)                                                                               \
    {                                                                                             \
        bf16x8 a[4];                                                                              \
        _Pragma("unroll")                                                                         \
        for (int i = 0; i < 4; ++i)                                                               \
            a[i] = *(const bf16x8*)&As[B][(wm + i * 16 + r) * EBK + q * 8];                       \
        _Pragma("unroll")                                                                         \
        for (int j = 0; j < 4; ++j) {                                                             \
            bf16x8 b = *(const bf16x8*)&Bs[B][(wn + j * 16 + r) * EBK + q * 8];                   \
            _Pragma("unroll")                                                                     \
            for (int i = 0; i < 4; ++i)                                                           \
                acc[i][j] = __builtin_amdgcn_mfma_f32_16x16x32_bf16(a[i], b, acc[i][j], 0, 0, 0); \
        }                                                                                         \
    }

// one steady-state step: wait(tile S, drain LDS reads) -> barrier -> stage(S+2) -> compute(S)
#define ESTEP(S)                         \
    {                                    \
        WAITBAR(4);                      \
        ESTAGE((S) + 2, ((S) + 2) % 3);  \
        ECOMPUTE((S) % 3);               \
    }

    ESTAGE(0, 0);
    ESTAGE(1, 1);
    ESTEP(0)  ESTEP(1)  ESTEP(2)  ESTEP(3)  ESTEP(4)  ESTEP(5)  ESTEP(6)
    ESTEP(7)  ESTEP(8)  ESTEP(9)  ESTEP(10) ESTEP(11) ESTEP(12) ESTEP(13)
    { WAITBAR(4); ECOMPUTE(2); }         // S = 14
    { WAITBAR(0); ECOMPUTE(0); }         // S = 15
#undef ESTAGE
#undef ECOMPUTE
#undef ESTEP

    int cols[4];
    float bias[4];
    #pragma unroll
    for (int j = 0; j < 4; ++j) {
        cols[j] = colBase + wn + j * 16 + r;
        bias[j] = b_edge[t * H + cols[j]];
    }
    #pragma unroll
    for (int i = 0; i < 4; ++i) {
        #pragma unroll
        for (int reg = 0; reg < 4; ++reg) {
            int row = wm + i * 16 + q * 4 + reg;
            int d = ls_dst[row];
            if (d < 0) continue;
            #pragma unroll
            for (int j = 0; j < 4; ++j)
                atomicAdd(&proposed[(size_t)d + cols[j]],
                          __float2int_rn((acc[i][j][reg] + bias[j]) * PSCALE));
        }
    }
}

// ---------------- fused GRU (MFMA, 128x64, 3-buf counted-vmcnt): A = AH[N][1024] ----------------
__global__ __launch_bounds__(256, 2)
void gru_mfma(const unsigned short* __restrict__ AH,
              const float* __restrict__ emb_f32,
              const unsigned short* __restrict__ Brt,
              const unsigned short* __restrict__ Bzt,
              const unsigned short* __restrict__ Bnt,
              const float* __restrict__ bir, const float* __restrict__ biz,
              const float* __restrict__ bin, const float* __restrict__ bhn,
              float* __restrict__ out, int N)
{
    __shared__ short As[3][GBM * GBK];    // 3 x 8KB linear
    __shared__ short Brs[3][GBN * GBK];   // 3 x 4KB
    __shared__ short Bzs[3][GBN * GBK];
    __shared__ short Bns[3][GBN * GBK];   // total 60KB -> 2 blocks/CU

    // XCD-aware swizzle (T1): contiguous logical-tile chunk per XCD.
    int wg = blockIdx.y * gridDim.x + blockIdx.x;
    const int nwg = gridDim.x * gridDim.y;
    if ((nwg & 7) == 0) {
        const int cpx = nwg >> 3;
        wg = (wg & 7) * cpx + (wg >> 3);
    }
    const int rowBase = (wg / gridDim.x) * GBM;
    const int colBase = (wg % gridDim.x) * GBN;

    const int tid = threadIdx.x;
    const int lane = tid & 63;
    const int wave = tid >> 6;
    const int wm = (wave >> 1) * 64;             // wave tile 64 rows x 32 cols
    const int wn = (wave & 1) * 32;
    const int q = lane >> 4;
    const int r = lane & 15;

    const int rA   = tid >> 2;                   // 0..63
    const int slot = (tid & 3) * 8;

    // all five staging streams are stride-1024 with compile-time S*GBK immediates
    const size_t aOff0 = (size_t)(rowBase + rA) * 1024 + slot;
    const size_t aOff1 = (size_t)(rowBase + 64 + rA) * 1024 + slot;
    const size_t bOff  = (size_t)(colBase + rA) * 1024 + slot;

    f32x4 accR[4][2], accZ[4][2], accNI[4][2], accNH[4][2];
    #pragma unroll
    for (int i = 0; i < 4; ++i)
        #pragma unroll
        for (int j = 0; j < 2; ++j) {
            accR[i][j] = (f32x4){0.f, 0.f, 0.f, 0.f};
            accZ[i][j] = accR[i][j];
            accNI[i][j] = accR[i][j];
            accNH[i][j] = accR[i][j];
        }

// stage K-step S (0..31) into buffer B (5 loads/thread, no selects)
#define GSTAGE(S, B)                                             \
    {                                                            \
        glds16(AH + aOff0 + (S) * GBK, &As[B][tid * 8]);         \
        glds16(AH + aOff1 + (S) * GBK, &As[B][(256 + tid) * 8]); \
        glds16(Brt + bOff + (S) * GBK, &Brs[B][tid * 8]);        \
        glds16(Bzt + bOff + (S) * GBK, &Bzs[B][tid * 8]);        \
        glds16(Bnt + bOff + (S) * GBK, &Bns[B][tid * 8]);        \
    }

// compute one K-step from buffer B; n-gate accumulator chosen at compile time
#define GCOMPUTE(ACCN, B)                                                                            \
    {                                                                                                \
        bf16x8 a[4];                                                                                 \
        _Pragma("unroll")                                                                            \
        for (int i = 0; i < 4; ++i)                                                                  \
            a[i] = *(const bf16x8*)&As[B][(wm + i * 16 + r) * GBK + q * 8];                          \
        _Pragma("unroll")                                                                            \
        for (int j = 0; j < 2; ++j) {                                                                \
            bf16x8 br = *(const bf16x8*)&Brs[B][(wn + j * 16 + r) * GBK + q * 8];                    \
            bf16x8 bz = *(const bf16x8*)&Bzs[B][(wn + j * 16 + r) * GBK + q * 8];                    \
            bf16x8 bn = *(const bf16x8*)&Bns[B][(wn + j * 16 + r) * GBK + q * 8];                    \
            _Pragma("unroll")                                                                        \
            for (int i = 0; i < 4; ++i) {                                                            \
                accR[i][j] = __builtin_amdgcn_mfma_f32_16x16x32_bf16(a[i], br, accR[i][j], 0, 0, 0); \
                accZ[i][j] = __builtin_amdgcn_mfma_f32_16x16x32_bf16(a[i], bz, accZ[i][j], 0, 0, 0); \
                ACCN[i][j] = __builtin_amdgcn_mfma_f32_16x16x32_bf16(a[i], bn, ACCN[i][j], 0, 0, 0); \
            }                                                                                        \
        }                                                                                            \
    }

// one steady-state step: wait(tile S, drain LDS reads) -> barrier -> stage(S+2) -> compute(S)
#define GSTEP(S, ACCN)                   \
    {                                    \
        WAITBAR(5);                      \
        GSTAGE((S) + 2, ((S) + 2) % 3);  \
        GCOMPUTE(ACCN, (S) % 3);         \
    }

    GSTAGE(0, 0);
    GSTAGE(1, 1);
    // K-steps 0..15: A = proposed half, n-gate -> accNI
    GSTEP(0,  accNI) GSTEP(1,  accNI) GSTEP(2,  accNI) GSTEP(3,  accNI)
    GSTEP(4,  accNI) GSTEP(5,  accNI) GSTEP(6,  accNI) GSTEP(7,  accNI)
    GSTEP(8,  accNI) GSTEP(9,  accNI) GSTEP(10, accNI) GSTEP(11, accNI)
    GSTEP(12, accNI) GSTEP(13, accNI) GSTEP(14, accNI) GSTEP(15, accNI)
    // K-steps 16..31: A = emb half, n-gate -> accNH
    GSTEP(16, accNH) GSTEP(17, accNH) GSTEP(18, accNH) GSTEP(19, accNH)
    GSTEP(20, accNH) GSTEP(21, accNH) GSTEP(22, accNH) GSTEP(23, accNH)
    GSTEP(24, accNH) GSTEP(25, accNH) GSTEP(26, accNH) GSTEP(27, accNH)
    GSTEP(28, accNH) GSTEP(29, accNH)
    { WAITBAR(5); GCOMPUTE(accNH, 0); }  // S = 30
    { WAITBAR(0); GCOMPUTE(accNH, 1); }  // S = 31
#undef GSTAGE
#undef GCOMPUTE
#undef GSTEP

    #pragma unroll
    for (int j = 0; j < 2; ++j) {
        const int col = colBase + wn + j * 16 + r;
        const float vbir = bir[col], vbiz = biz[col], vbin = bin[col], vbhn = bhn[col];
        #pragma unroll
        for (int i = 0; i < 4; ++i) {
            #pragma unroll
            for (int reg = 0; reg < 4; ++reg) {
                const int row = rowBase + wm + i * 16 + q * 4 + reg;
                if (row >= N) continue;
                float rg = sigmoidf_(accR[i][j][reg] + vbir);
                float zg = sigmoidf_(accZ[i][j][reg] + vbiz);
                float ng = tanhf(accNI[i][j][reg] + vbin + rg * (accNH[i][j][reg] + vbhn));
                float h = emb_f32[(size_t)row * H + col];
                out[(size_t)row * H + col] = (1.0f - zg) * ng + zg * h;
            }
        }
    }
}

extern "C" void kernel_launch(void* const* d_in, const int* in_sizes, int n_in,
                              void* d_out, int out_size, void* d_ws, size_t ws_size,
                              hipStream_t stream) {
    const float* emb     = (const float*)d_in[0];
    const int*   src_idx = (const int*)d_in[1];
    const int*   dst_idx = (const int*)d_in[2];
    const int*   etype   = (const int*)d_in[3];
    const float* W_edge  = (const float*)d_in[6];
    const float* b_edge  = (const float*)d_in[7];
    const float* Wir = (const float*)d_in[8];
    const float* Wiz = (const float*)d_in[9];
    const float* Win = (const float*)d_in[10];
    const float* bir = (const float*)d_in[11];
    const float* biz = (const float*)d_in[12];
    const float* bin = (const float*)d_in[13];
    const float* Whr = (const float*)d_in[14];
    const float* Whz = (const float*)d_in[15];
    const float* Whn = (const float*)d_in[16];
    const float* bhn = (const float*)d_in[17];

    const int E = in_sizes[1];
    const int N = in_sizes[0] / H;
    const int NH = N * H;

    char* ws = (char*)d_ws;
    int*            proposed = (int*)ws;                         ws += (size_t)NH * 4;  // fixed-point
    unsigned short* AH       = (unsigned short*)ws;              ws += (size_t)NH * 2 * 2;  // [N][1024]
    unsigned short* Brt      = (unsigned short*)ws;              ws += 512 * 1024 * 2;
    unsigned short* Bzt      = (unsigned short*)ws;              ws += 512 * 1024 * 2;
    unsigned short* Bnt      = (unsigned short*)ws;              ws += 512 * 1024 * 2;
    unsigned short* WeT      = (unsigned short*)ws;              ws += 3072 * 512 * 2;
    int*            meta     = (int*)ws;                         ws += 32 * 4;
    int*            perm     = (int*)ws;
    const int maxRowTiles = (E + EBM - 1) / EBM + NT;

    hipMemsetAsync(proposed, 0, (size_t)NH * 4, stream);
    hipMemsetAsync(meta, 0, 32 * 4, stream);
    hipMemsetAsync(perm, 0xFF, (size_t)maxRowTiles * EBM * 4, stream);

    const int n4 = NH / 4;
    conv_to_ah<<<(n4 + 255) / 256, 256, 0, stream>>>(emb, AH, n4, 1);       // emb -> high half
    conv_gru_w_kernel<<<(512 * 1024 + 255) / 256, 256, 0, stream>>>(
        Wir, Wiz, Win, Whr, Whz, Whn, Brt, Bzt, Bnt);
    conv_edge_w_kernel<<<(3072 * 512 + 255) / 256, 256, 0, stream>>>(W_edge, WeT);

    hist_kernel<<<(E + 255) / 256, 256, 0, stream>>>(etype, E, meta);
    prefix_kernel<<<1, 64, 0, stream>>>(meta);
    scatter_perm_kernel<<<(E + 255) / 256, 256, 0, stream>>>(etype, E, meta, perm);

    dim3 egrid(H / EBN, maxRowTiles);
    edge_msg_mfma<<<egrid, 256, 0, stream>>>(AH, src_idx, dst_idx, b_edge, WeT,
                                             meta, perm, proposed);

    conv_i2ah<<<(n4 + 255) / 256, 256, 0, stream>>>(proposed, AH, n4);      // proposed -> low half

    dim3 ggrid(H / GBN, (N + GBM - 1) / GBM);
    gru_mfma<<<ggrid, 256, 0, stream>>>(AH, emb, Brt, Bzt, Bnt,
                                        bir, biz, bin, bhn, (float*)d_out, N);
}